// Round 7
// baseline (333.441 us; speedup 1.0000x reference)
//
#include <hip/hip_runtime.h>
#include <stdint.h>

#define DM 1024
#define DK 128
#define SEQ 4096
#define NB 4
#define NSPLIT 4
#define KSPAN (SEQ / NSPLIT)
#define NQT (SEQ / 128)

typedef float f32x4 __attribute__((ext_vector_type(4)));
typedef float f32x16 __attribute__((ext_vector_type(16)));
typedef __bf16 bf16x8 __attribute__((ext_vector_type(8)));
typedef unsigned short u16x8 __attribute__((ext_vector_type(8)));
typedef unsigned short u16x4 __attribute__((ext_vector_type(4)));

__device__ __forceinline__ unsigned short f2bf(float f) {
    unsigned int u = __builtin_bit_cast(unsigned int, f);
    u += 0x7fffu + ((u >> 16) & 1u);
    return (unsigned short)(u >> 16);
}
__device__ __forceinline__ float bf2f(unsigned short h) {
    unsigned int u = ((unsigned int)h) << 16;
    return __builtin_bit_cast(float, u);
}
__device__ __forceinline__ f32x4 mfma16b(bf16x8 a, u16x8 b, f32x4 c) {
    return __builtin_amdgcn_mfma_f32_16x16x32_bf16(
        a, __builtin_bit_cast(bf16x8, b), c, 0, 0, 0);
}
__device__ __forceinline__ f32x16 mfma32(u16x8 a, u16x8 b, f32x16 c) {
    return __builtin_amdgcn_mfma_f32_32x32x16_bf16(
        __builtin_bit_cast(bf16x8, a), __builtin_bit_cast(bf16x8, b), c, 0, 0, 0);
}

// fp32 pair -> bf16x8 (compiler emits v_cvt_pk_bf16_f32 pairs, RNE — same
// rounding as f2bf).
__device__ __forceinline__ bf16x8 cvt84(f32x4 lo, f32x4 hi) {
    bf16x8 r;
    r[0] = (__bf16)lo[0]; r[1] = (__bf16)lo[1]; r[2] = (__bf16)lo[2]; r[3] = (__bf16)lo[3];
    r[4] = (__bf16)hi[0]; r[5] = (__bf16)hi[1]; r[6] = (__bf16)hi[2]; r[7] = (__bf16)hi[3];
    return r;
}

// ---------------- Kernel A: wT[mat][d][k] = w[mat][k][d] (fp32 -> bf16) -----
__global__ __launch_bounds__(256) void wt_kernel(
        const float* __restrict__ wq, const float* __restrict__ wk,
        const float* __restrict__ wv, unsigned short* __restrict__ wT) {
    __shared__ unsigned short T[64 * 72];
    const int kt = blockIdx.x, dt = blockIdx.y, mat = blockIdx.z;
    const float* src = (mat == 0) ? wq : (mat == 1 ? wk : wv);
    const int tid = threadIdx.x;
    const int rb = tid >> 4, c4 = (tid & 15) * 4;
    float4 x[4];
#pragma unroll
    for (int i = 0; i < 4; i++)
        x[i] = *(const float4*)&src[(size_t)(kt * 64 + i * 16 + rb) * DK + dt * 64 + c4];
#pragma unroll
    for (int i = 0; i < 4; i++) {
        const int row = i * 16 + rb;
        T[(c4 + 0) * 72 + row] = f2bf(x[i].x);
        T[(c4 + 1) * 72 + row] = f2bf(x[i].y);
        T[(c4 + 2) * 72 + row] = f2bf(x[i].z);
        T[(c4 + 3) * 72 + row] = f2bf(x[i].w);
    }
    __syncthreads();
    const int dl = tid >> 2, ks0 = (tid & 3) * 16;
    unsigned short* dst = wT + (size_t)mat * DM * DK + (size_t)(dt * 64 + dl) * DM + kt * 64 + ks0;
#pragma unroll
    for (int j = 0; j < 2; j++)
        *(u16x8*)&dst[8 * j] = *(const u16x8*)&T[dl * 72 + ks0 + 8 * j];
}

// ---------------- Kernel B: merged projections, NO-LDS streaming -----------
// R10: three pipeline variants over global_load_lds (R8/R9/R10) timed
// IDENTICALLY (~90us, MfmaUtil 5%) — the waitcnt pass drains vmcnt before any
// ds_read while LDS-DMA is outstanding, regardless of buffer disjointness.
// Falsifier fired => abandon LDS staging entirely. The A-fragment is 32B
// CONTIGUOUS fp32 per lane (X[t0+l16+16mf][kk+quad*8..+8]) and B is 16B
// contiguous bf16 (WT[32w+16nf+l16][kk+quad*8..+8]) — both direct-loadable
// global->VGPR. X has zero intra-block reuse (LDS bought nothing); W is
// L2-resident (256KB/mat, 192MB L2 traffic ~6us aggregate). No barriers in
// the loop => compiler hoists loads freely; no LDS limit => ~4 blocks/CU of
// TLP. Depth-1 register prefetch of the A-stream (named vars, static idx).
__global__ __launch_bounds__(256)
void proj_kernel(
        const float* __restrict__ qin, const float* __restrict__ kin,
        const float* __restrict__ vin, const unsigned short* __restrict__ wT,
        const float* __restrict__ bq, const float* __restrict__ bk,
        const float* __restrict__ bv,
        unsigned short* __restrict__ qp, unsigned short* __restrict__ kp,
        unsigned short* __restrict__ vpT) {
    __shared__ unsigned short Tb[128 * 72];  // only used by y==2 epilogue

    const int y = blockIdx.y;
    const float* X = (y == 0) ? qin : (y == 1 ? kin : vin);
    const unsigned short* WTm = wT + (size_t)y * (DM * DK);
    const float* bias = (y == 0) ? bq : (y == 1 ? bk : bv);

    const int tid = threadIdx.x;
    const int w = tid >> 6, lane = tid & 63, l16 = lane & 15, quad = lane >> 4;
    const int t0 = blockIdx.x * 64;

    // lane-base pointers: 32B/lane contiguous A, 16B/lane contiguous B
    const float* xb = X + (size_t)(t0 + l16) * DM + quad * 8;
    const unsigned short* wb = WTm + (size_t)(32 * w + l16) * DM + quad * 8;

    f32x4 zero = {0.f, 0.f, 0.f, 0.f};
    f32x4 acc[4][2];
#pragma unroll
    for (int mf = 0; mf < 4; mf++)
#pragma unroll
        for (int nf = 0; nf < 2; nf++) acc[mf][nf] = zero;

    // depth-1 prefetch of the A-stream (the HBM-bound stream)
    f32x4 alo[4], ahi[4];
#pragma unroll
    for (int mf = 0; mf < 4; mf++) {
        const float* p = xb + (size_t)mf * (16 * DM);
        alo[mf] = *(const f32x4*)p;
        ahi[mf] = *(const f32x4*)(p + 4);
    }

    for (int t = 0; t < 32; ++t) {
        const int kn = (t < 31 ? t + 1 : t) * 32;  // last iter re-touches (L1-hot)
        f32x4 nlo[4], nhi[4];
#pragma unroll
        for (int mf = 0; mf < 4; mf++) {
            const float* p = xb + (size_t)mf * (16 * DM) + kn;
            nlo[mf] = *(const f32x4*)p;
            nhi[mf] = *(const f32x4*)(p + 4);
        }
        u16x8 bv0 = *(const u16x8*)(wb + t * 32);
        u16x8 bv1 = *(const u16x8*)(wb + 16 * DM + t * 32);
#pragma unroll
        for (int mf = 0; mf < 4; mf++) {
            bf16x8 av = cvt84(alo[mf], ahi[mf]);
            acc[mf][0] = mfma16b(av, bv0, acc[mf][0]);
            acc[mf][1] = mfma16b(av, bv1, acc[mf][1]);
        }
#pragma unroll
        for (int mf = 0; mf < 4; mf++) { alo[mf] = nlo[mf]; ahi[mf] = nhi[mf]; }
    }

    if (y < 2) {
        unsigned short* outp = y ? kp : qp;
#pragma unroll
        for (int nf = 0; nf < 2; nf++) {
            const int n = l16 + 32 * w + 16 * nf;
            const float bb = bias[n];
#pragma unroll
            for (int mf = 0; mf < 4; mf++)
#pragma unroll
                for (int r = 0; r < 4; r++)
                    outp[(size_t)(t0 + 16 * mf + quad * 4 + r) * DK + n] = f2bf(acc[mf][nf][r] + bb);
        }
    } else {
#pragma unroll
        for (int nf = 0; nf < 2; nf++) {
            const int d = l16 + 32 * w + 16 * nf;
            const float bb = bias[d];
#pragma unroll
            for (int mf = 0; mf < 4; mf++)
#pragma unroll
                for (int r = 0; r < 4; r++)
                    Tb[d * 72 + 16 * mf + quad * 4 + r] = f2bf(acc[mf][nf][r] + bb);
        }
        __syncthreads();
        const int d2 = tid >> 1, ts = (tid & 1) * 32;
        const int b2 = t0 >> 12, tl0 = t0 & (SEQ - 1);
#pragma unroll
        for (int j = 0; j < 4; j++)
            *(u16x8*)&vpT[((size_t)(b2 * DK + d2)) * SEQ + tl0 + ts + 8 * j] =
                *(const u16x8*)&Tb[d2 * 72 + ts + 8 * j];
    }
}

// ---------------- Kernel C: flash attention partials -----------------------
// waves_per_eu(2,2): grid 512 = exactly 2 blocks/CU; raise VGPR budget to 256
// so kbuf/vbuf prefetch stays live across the MFMA section.
__global__ __launch_bounds__(256)
__attribute__((amdgpu_waves_per_eu(2, 2)))
void attn_part_kernel(
        const unsigned short* __restrict__ qp, const unsigned short* __restrict__ kp,
        const unsigned short* __restrict__ vpT,
        unsigned short* __restrict__ Opart, float* __restrict__ Lw) {
    __shared__ unsigned short Ks[64 * 136];  // [key][d]
    __shared__ unsigned short Vs[128 * 72];  // [d][key]

    const int tid = threadIdx.x;
    const int w = tid >> 6, lane = tid & 63, l32 = lane & 31, h = lane >> 5;
    const int qt = blockIdx.x, pi = blockIdx.y, b = blockIdx.z;
    const int q0 = qt * 128;
    const int kbase = pi * KSPAN;
    const float csc = 0.08838834764831845f * 1.4426950408889634f;  // scale*log2(e)

    u16x8 qf[8];
    {
        const unsigned short* qrow = qp + (size_t)(b * SEQ + q0 + 32 * w + l32) * DK + 8 * h;
#pragma unroll
        for (int c = 0; c < 8; c++) qf[c] = *(const u16x8*)&qrow[16 * c];
    }

    f32x16 oacc[4];
#pragma unroll
    for (int i = 0; i < 4; i++)
#pragma unroll
        for (int j = 0; j < 16; j++) oacc[i][j] = 0.f;
    float l_acc = 0.f;

    const int krow = tid >> 2, kch = (tid & 3) * 8;
    const int vrow = tid >> 1, voff = (tid & 1) * 8;
    uint4 kbuf[4], vbuf[4];
    {
        const unsigned short* kg = kp + (size_t)(b * SEQ + kbase + krow) * DK + kch;
        const unsigned short* vg = vpT + (size_t)(b * DK + vrow) * SEQ + kbase + voff;
#pragma unroll
        for (int i = 0; i < 4; i++) {
            kbuf[i] = *(const uint4*)&kg[32 * i];
            vbuf[i] = *(const uint4*)&vg[16 * i];
        }
    }

    for (int it = 0; it < KSPAN / 64; it++) {
        __syncthreads();
#pragma unroll
        for (int i = 0; i < 4; i++) {
            *(u16x8*)&Ks[krow * 136 + kch + 32 * i] = __builtin_bit_cast(u16x8, kbuf[i]);
            *(u16x8*)&Vs[vrow * 72 + voff + 16 * i] = __builtin_bit_cast(u16x8, vbuf[i]);
        }
        __syncthreads();
        if (it + 1 < KSPAN / 64) {
            const int kn = kbase + (it + 1) * 64;
            const unsigned short* kg = kp + (size_t)(b * SEQ + kn + krow) * DK + kch;
            const unsigned short* vg = vpT + (size_t)(b * DK + vrow) * SEQ + kn + voff;
#pragma unroll
            for (int i = 0; i < 4; i++) {
                kbuf[i] = *(const uint4*)&kg[32 * i];
                vbuf[i] = *(const uint4*)&vg[16 * i];
            }
        }
        f32x16 sacc[2];
#pragma unroll
        for (int kb = 0; kb < 2; kb++)
#pragma unroll
            for (int j = 0; j < 16; j++) sacc[kb][j] = 0.f;
#pragma unroll
        for (int c = 0; c < 8; c++)
#pragma unroll
            for (int kb = 0; kb < 2; kb++) {
                u16x8 kf = *(const u16x8*)&Ks[(l32 + 32 * kb) * 136 + 16 * c + 8 * h];
                sacc[kb] = mfma32(kf, qf[c], sacc[kb]);
            }
        unsigned int pp[16];
#pragma unroll
        for (int kb = 0; kb < 2; kb++)
#pragma unroll
            for (int r2 = 0; r2 < 8; r2++) {
                float p0 = exp2f(sacc[kb][2 * r2] * csc);
                float p1 = exp2f(sacc[kb][2 * r2 + 1] * csc);
                l_acc += p0 + p1;
                pp[kb * 8 + r2] = (unsigned int)f2bf(p0) | ((unsigned int)f2bf(p1) << 16);
            }
#pragma unroll
        for (int c = 0; c < 4; c++) {
            const int bs = (c >> 1) * 8 + (c & 1) * 4;
            unsigned int o0 = pp[bs], o1 = pp[bs + 1], o2 = pp[bs + 2], o3 = pp[bs + 3];
            unsigned int x0 = __shfl_xor(o0, 32), x1 = __shfl_xor(o1, 32);
            unsigned int x2 = __shfl_xor(o2, 32), x3 = __shfl_xor(o3, 32);
            uint4 af;
            af.x = h ? x2 : o0;
            af.y = h ? x3 : o1;
            af.z = h ? o2 : x0;
            af.w = h ? o3 : x1;
            u16x8 afr = __builtin_bit_cast(u16x8, af);
#pragma unroll
            for (int db = 0; db < 4; db++) {
                u16x8 vf = *(const u16x8*)&Vs[(32 * db + l32) * 72 + 16 * c + 8 * h];
                oacc[db] = mfma32(afr, vf, oacc[db]);
            }
        }
    }
    float l_tot = l_acc + __shfl_xor(l_acc, 32);
    if (lane < 32)
        Lw[(size_t)(b * NSPLIT + pi) * SEQ + q0 + 32 * w + l32] = l_tot;
    float rl[16];
#pragma unroll
    for (int r = 0; r < 16; r++) {
        int qr = (r & 3) + 8 * (r >> 2) + 4 * h;
        rl[r] = 1.f / __shfl(l_tot, qr);
    }
    unsigned short* ob = Opart + ((size_t)((b * NSPLIT + pi) * NQT + qt)) * 16384 + (size_t)tid * 64;
#pragma unroll
    for (int db = 0; db < 4; db++) {
        u16x8 s0, s1;
#pragma unroll
        for (int j = 0; j < 8; j++) {
            s0[j] = f2bf(oacc[db][j] * rl[j]);
            s1[j] = f2bf(oacc[db][8 + j] * rl[8 + j]);
        }
        *(u16x8*)&ob[db * 16] = s0;
        *(u16x8*)&ob[db * 16 + 8] = s1;
    }
}

// ---------------- Kernel D: combine splits (d-split, 256 blocks) -----------
__global__ __launch_bounds__(256) void attn_combine_kernel(
        const unsigned short* __restrict__ Opart, const float* __restrict__ Lw,
        float* __restrict__ out) {
    __shared__ float Ls[NSPLIT * 128];
    const int tid = threadIdx.x;
    const int w = tid >> 6, lane = tid & 63, l32 = lane & 31, h = lane >> 5;
    const int qt = blockIdx.x, b = blockIdx.y, z = blockIdx.z;
    const int q0 = qt * 128;
    for (int i = tid; i < NSPLIT * 128; i += 256) {
        int pi = i >> 7, ql = i & 127;
        Ls[i] = Lw[(size_t)(b * NSPLIT + pi) * SEQ + q0 + ql];
    }
    __syncthreads();
    int qlr[16];
    float inv[16];
#pragma unroll
    for (int r = 0; r < 16; r++) {
        qlr[r] = 32 * w + (r & 3) + 8 * (r >> 2) + 4 * h;
        float s = 0.f;
#pragma unroll
        for (int pi = 0; pi < NSPLIT; pi++) s += Ls[pi * 128 + qlr[r]];
        inv[r] = 1.f / s;
    }
    float acc[32];
#pragma unroll
    for (int i = 0; i < 32; i++) acc[i] = 0.f;
#pragma unroll
    for (int pi = 0; pi < NSPLIT; pi++) {
        float wr[16];
#pragma unroll
        for (int r = 0; r < 16; r++) wr[r] = Ls[pi * 128 + qlr[r]] * inv[r];
        const unsigned short* ob =
            Opart + ((size_t)((b * NSPLIT + pi) * NQT + qt)) * 16384 + (size_t)tid * 64;
#pragma unroll
        for (int j = 0; j < 2; j++) {
            const int db = 2 * z + j;
#pragma unroll
            for (int hf = 0; hf < 2; hf++) {
                u16x8 v8 = *(const u16x8*)&ob[db * 16 + 8 * hf];
#pragma unroll
                for (int jj = 0; jj < 8; jj++)
                    acc[j * 16 + 8 * hf + jj] += wr[8 * hf + jj] * bf2f(v8[jj]);
            }
        }
    }
#pragma unroll
    for (int j = 0; j < 2; j++) {
        const int db = 2 * z + j;
#pragma unroll
        for (int r = 0; r < 16; r++)
            out[(size_t)(b * SEQ + q0 + qlr[r]) * DK + 32 * db + l32] = acc[j * 16 + r];
    }
}

extern "C" void kernel_launch(void* const* d_in, const int* in_sizes, int n_in,
                              void* d_out, int out_size, void* d_ws, size_t ws_size,
                              hipStream_t stream) {
    const float* q  = (const float*)d_in[0];
    const float* k  = (const float*)d_in[1];
    const float* v  = (const float*)d_in[2];
    const float* wq = (const float*)d_in[3];
    const float* bq = (const float*)d_in[4];
    const float* wk = (const float*)d_in[5];
    const float* bk = (const float*)d_in[6];
    const float* wv = (const float*)d_in[7];
    const float* bv = (const float*)d_in[8];
    float* out = (float*)d_out;

    char* ws = (char*)d_ws;
    unsigned short* wT    = (unsigned short*)(ws);                    // 768 KB
    unsigned short* qp    = (unsigned short*)(ws + (1u << 20));       // 4 MB
    unsigned short* kpb   = (unsigned short*)(ws + (5u << 20));       // 4 MB
    unsigned short* vpT   = (unsigned short*)(ws + (9u << 20));       // 4 MB
    unsigned short* Opart = (unsigned short*)(ws + (13u << 20));      // 16 MB
    float* Lw             = (float*)(ws + (29u << 20));               // 256 KB

    hipLaunchKernelGGL(wt_kernel, dim3(16, 2, 3), dim3(256), 0, stream, wq, wk, wv, wT);
    hipLaunchKernelGGL(proj_kernel, dim3(256, 3), dim3(256), 0, stream,
                       q, k, v, wT, bq, bk, bv, qp, kpb, vpT);
    hipLaunchKernelGGL(attn_part_kernel, dim3(NQT, NSPLIT, NB), dim3(256), 0, stream,
                       qp, kpb, vpT, Opart, Lw);
    hipLaunchKernelGGL(attn_combine_kernel, dim3(NQT, NB, 2), dim3(256), 0, stream,
                       Opart, Lw, out);
}

// Round 8
// 299.639 us; speedup vs baseline: 1.1128x; 1.1128x over previous
//
#include <hip/hip_runtime.h>
#include <stdint.h>

#define DM 1024
#define DK 128
#define SEQ 4096
#define NB 4
#define NSPLIT 4
#define KSPAN (SEQ / NSPLIT)
#define NQT (SEQ / 128)

typedef float f32x4 __attribute__((ext_vector_type(4)));
typedef float f32x16 __attribute__((ext_vector_type(16)));
typedef __bf16 bf16x8 __attribute__((ext_vector_type(8)));
typedef unsigned short u16x8 __attribute__((ext_vector_type(8)));
typedef unsigned short u16x4 __attribute__((ext_vector_type(4)));

__device__ __forceinline__ unsigned short f2bf(float f) {
    unsigned int u = __builtin_bit_cast(unsigned int, f);
    u += 0x7fffu + ((u >> 16) & 1u);
    return (unsigned short)(u >> 16);
}
__device__ __forceinline__ float bf2f(unsigned short h) {
    unsigned int u = ((unsigned int)h) << 16;
    return __builtin_bit_cast(float, u);
}
__device__ __forceinline__ f32x4 mfma16(u16x8 a, u16x8 b, f32x4 c) {
    return __builtin_amdgcn_mfma_f32_16x16x32_bf16(
        __builtin_bit_cast(bf16x8, a), __builtin_bit_cast(bf16x8, b), c, 0, 0, 0);
}
__device__ __forceinline__ f32x16 mfma32(u16x8 a, u16x8 b, f32x16 c) {
    return __builtin_amdgcn_mfma_f32_32x32x16_bf16(
        __builtin_bit_cast(bf16x8, a), __builtin_bit_cast(bf16x8, b), c, 0, 0, 0);
}

// ---------------- Kernel A: wT[mat][d][k] = w[mat][k][d] (fp32 -> bf16) -----
__global__ __launch_bounds__(256) void wt_kernel(
        const float* __restrict__ wq, const float* __restrict__ wk,
        const float* __restrict__ wv, unsigned short* __restrict__ wT) {
    __shared__ unsigned short T[64 * 72];
    const int kt = blockIdx.x, dt = blockIdx.y, mat = blockIdx.z;
    const float* src = (mat == 0) ? wq : (mat == 1 ? wk : wv);
    const int tid = threadIdx.x;
    const int rb = tid >> 4, c4 = (tid & 15) * 4;
    float4 x[4];
#pragma unroll
    for (int i = 0; i < 4; i++)
        x[i] = *(const float4*)&src[(size_t)(kt * 64 + i * 16 + rb) * DK + dt * 64 + c4];
#pragma unroll
    for (int i = 0; i < 4; i++) {
        const int row = i * 16 + rb;
        T[(c4 + 0) * 72 + row] = f2bf(x[i].x);
        T[(c4 + 1) * 72 + row] = f2bf(x[i].y);
        T[(c4 + 2) * 72 + row] = f2bf(x[i].z);
        T[(c4 + 3) * 72 + row] = f2bf(x[i].w);
    }
    __syncthreads();
    const int dl = tid >> 2, ks0 = (tid & 3) * 16;
    unsigned short* dst = wT + (size_t)mat * DM * DK + (size_t)(dt * 64 + dl) * DM + kt * 64 + ks0;
#pragma unroll
    for (int j = 0; j < 2; j++)
        *(u16x8*)&dst[8 * j] = *(const u16x8*)&T[dl * 72 + ks0 + 8 * j];
}

// ---------------- Kernel B: merged projections, high-occupancy tiles -------
// R11 post-mortem chain: every structure (reg->LDS 77-90us, global_load_lds
// 88-92us x3 variants, no-LDS streaming 137us) was latency-serialized with
// OccupancyPercent 16-27% — because grid 768 = 3 blocks/CU = 12 waves/CU is
// a HARD cap. The lever is TLP, not ILP: rows/block 64->32, BK 128->64 =>
// grid (512,3)=1536 blocks = 6 blocks/CU = 24 waves/CU. LDS 21KB (<26.7KB
// for 6 blocks/CU); prefetch payload 24 VGPR (vs 64) so liveness pressure
// dissolves. Structure = the measured-best reg->LDS 2-barrier loop.
// Row pad 66 shorts (33 dwords, odd): frag-read bank = row*33%32 = row,
// conflict-free; staging writes <=2-way (free, m136).
__global__ __launch_bounds__(256)
void proj_kernel(
        const float* __restrict__ qin, const float* __restrict__ kin,
        const float* __restrict__ vin, const unsigned short* __restrict__ wT,
        const float* __restrict__ bq, const float* __restrict__ bk,
        const float* __restrict__ bv,
        unsigned short* __restrict__ qp, unsigned short* __restrict__ kp,
        unsigned short* __restrict__ vpT) {
    __shared__ unsigned short Xs[32 * 66];   // [row][BK=64 +2pad] bf16, 4.2 KB
    __shared__ unsigned short Ws[128 * 66];  // [ncol][BK=64 +2pad] bf16, 16.9 KB

    const int y = blockIdx.y;
    const float* X = (y == 0) ? qin : (y == 1 ? kin : vin);
    const unsigned short* WTm = wT + (size_t)y * (DM * DK);
    const float* bias = (y == 0) ? bq : (y == 1 ? bk : bv);

    const int tid = threadIdx.x;
    const int w = tid >> 6, lane = tid & 63, l16 = lane & 15, quad = lane >> 4;
    const int t0 = blockIdx.x * 32;

    // staging geometry: X tile 32x64 fp32 (8 floats/thread, 256B/row run),
    // W tile 128x64 bf16 (32 shorts/thread, 64B contiguous)
    const int xr = tid >> 3, xc = (tid & 7) * 8;
    const int wr = tid >> 1, wc = (tid & 1) * 32;
    const float* xg = X + (size_t)(t0 + xr) * DM + xc;
    const unsigned short* wg = WTm + (size_t)wr * DM + wc;

    f32x4 zero = {0.f, 0.f, 0.f, 0.f};
    f32x4 acc[2][2];
#pragma unroll
    for (int mf = 0; mf < 2; mf++)
#pragma unroll
        for (int nf = 0; nf < 2; nf++) acc[mf][nf] = zero;

    // register prefetch (depth 1): 8 fp32 + 32 bf16 = 24 VGPR
    float4 xv0 = *(const float4*)xg;
    float4 xv1 = *(const float4*)(xg + 4);
    uint4 wvv[4];
#pragma unroll
    for (int j = 0; j < 4; j++) wvv[j] = *(const uint4*)(wg + 8 * j);

    for (int t = 0; t < 16; ++t) {
        __syncthreads();
        {
            u16x8 px;
            px[0] = f2bf(xv0.x); px[1] = f2bf(xv0.y);
            px[2] = f2bf(xv0.z); px[3] = f2bf(xv0.w);
            px[4] = f2bf(xv1.x); px[5] = f2bf(xv1.y);
            px[6] = f2bf(xv1.z); px[7] = f2bf(xv1.w);
            *(u16x8*)&Xs[xr * 66 + xc] = px;
#pragma unroll
            for (int j = 0; j < 4; j++)
                *(u16x8*)&Ws[wr * 66 + wc + 8 * j] = __builtin_bit_cast(u16x8, wvv[j]);
        }
        __syncthreads();
        if (t < 15) {
            xg += 64;
            wg += 64;
            xv0 = *(const float4*)xg;
            xv1 = *(const float4*)(xg + 4);
#pragma unroll
            for (int j = 0; j < 4; j++) wvv[j] = *(const uint4*)(wg + 8 * j);
        }
#pragma unroll
        for (int ks = 0; ks < 2; ks++) {
            u16x8 av[2], bvf[2];
#pragma unroll
            for (int mf = 0; mf < 2; mf++)
                av[mf] = *(const u16x8*)&Xs[(l16 + 16 * mf) * 66 + ks * 32 + quad * 8];
#pragma unroll
            for (int nf = 0; nf < 2; nf++)
                bvf[nf] = *(const u16x8*)&Ws[(32 * w + 16 * nf + l16) * 66 + ks * 32 + quad * 8];
#pragma unroll
            for (int mf = 0; mf < 2; mf++)
#pragma unroll
                for (int nf = 0; nf < 2; nf++)
                    acc[mf][nf] = mfma16(av[mf], bvf[nf], acc[mf][nf]);
        }
    }

    if (y < 2) {
        unsigned short* outp = y ? kp : qp;
#pragma unroll
        for (int nf = 0; nf < 2; nf++) {
            const int n = l16 + 32 * w + 16 * nf;
            const float bb = bias[n];
#pragma unroll
            for (int mf = 0; mf < 2; mf++)
#pragma unroll
                for (int r = 0; r < 4; r++)
                    outp[(size_t)(t0 + 16 * mf + quad * 4 + r) * DK + n] = f2bf(acc[mf][nf][r] + bb);
        }
    } else {
        __syncthreads();
        unsigned short* Tb = Ws;  // [128 d][36 pad] overlay, 9.2 KB, loop done
#pragma unroll
        for (int nf = 0; nf < 2; nf++) {
            const int d = l16 + 32 * w + 16 * nf;
            const float bb = bias[d];
#pragma unroll
            for (int mf = 0; mf < 2; mf++)
#pragma unroll
                for (int r = 0; r < 4; r++)
                    Tb[d * 36 + 16 * mf + quad * 4 + r] = f2bf(acc[mf][nf][r] + bb);
        }
        __syncthreads();
        const int d2 = tid >> 1, ts = (tid & 1) * 16;
        const int b2 = t0 >> 12, tl0 = t0 & (SEQ - 1);
#pragma unroll
        for (int j = 0; j < 2; j++)
            *(u16x8*)&vpT[((size_t)(b2 * DK + d2)) * SEQ + tl0 + ts + 8 * j] =
                *(const u16x8*)&Tb[d2 * 36 + ts + 8 * j];
    }
}

// ---------------- Kernel C: flash attention partials -----------------------
// waves_per_eu(2,2): grid 512 = exactly 2 blocks/CU; raise VGPR budget to 256
// so kbuf/vbuf prefetch stays live across the MFMA section.
__global__ __launch_bounds__(256)
__attribute__((amdgpu_waves_per_eu(2, 2)))
void attn_part_kernel(
        const unsigned short* __restrict__ qp, const unsigned short* __restrict__ kp,
        const unsigned short* __restrict__ vpT,
        unsigned short* __restrict__ Opart, float* __restrict__ Lw) {
    __shared__ unsigned short Ks[64 * 136];  // [key][d]
    __shared__ unsigned short Vs[128 * 72];  // [d][key]

    const int tid = threadIdx.x;
    const int w = tid >> 6, lane = tid & 63, l32 = lane & 31, h = lane >> 5;
    const int qt = blockIdx.x, pi = blockIdx.y, b = blockIdx.z;
    const int q0 = qt * 128;
    const int kbase = pi * KSPAN;
    const float csc = 0.08838834764831845f * 1.4426950408889634f;  // scale*log2(e)

    u16x8 qf[8];
    {
        const unsigned short* qrow = qp + (size_t)(b * SEQ + q0 + 32 * w + l32) * DK + 8 * h;
#pragma unroll
        for (int c = 0; c < 8; c++) qf[c] = *(const u16x8*)&qrow[16 * c];
    }

    f32x16 oacc[4];
#pragma unroll
    for (int i = 0; i < 4; i++)
#pragma unroll
        for (int j = 0; j < 16; j++) oacc[i][j] = 0.f;
    float l_acc = 0.f;

    const int krow = tid >> 2, kch = (tid & 3) * 8;
    const int vrow = tid >> 1, voff = (tid & 1) * 8;
    uint4 kbuf[4], vbuf[4];
    {
        const unsigned short* kg = kp + (size_t)(b * SEQ + kbase + krow) * DK + kch;
        const unsigned short* vg = vpT + (size_t)(b * DK + vrow) * SEQ + kbase + voff;
#pragma unroll
        for (int i = 0; i < 4; i++) {
            kbuf[i] = *(const uint4*)&kg[32 * i];
            vbuf[i] = *(const uint4*)&vg[16 * i];
        }
    }

    for (int it = 0; it < KSPAN / 64; it++) {
        __syncthreads();
#pragma unroll
        for (int i = 0; i < 4; i++) {
            *(u16x8*)&Ks[krow * 136 + kch + 32 * i] = __builtin_bit_cast(u16x8, kbuf[i]);
            *(u16x8*)&Vs[vrow * 72 + voff + 16 * i] = __builtin_bit_cast(u16x8, vbuf[i]);
        }
        __syncthreads();
        if (it + 1 < KSPAN / 64) {
            const int kn = kbase + (it + 1) * 64;
            const unsigned short* kg = kp + (size_t)(b * SEQ + kn + krow) * DK + kch;
            const unsigned short* vg = vpT + (size_t)(b * DK + vrow) * SEQ + kn + voff;
#pragma unroll
            for (int i = 0; i < 4; i++) {
                kbuf[i] = *(const uint4*)&kg[32 * i];
                vbuf[i] = *(const uint4*)&vg[16 * i];
            }
        }
        f32x16 sacc[2];
#pragma unroll
        for (int kb = 0; kb < 2; kb++)
#pragma unroll
            for (int j = 0; j < 16; j++) sacc[kb][j] = 0.f;
#pragma unroll
        for (int c = 0; c < 8; c++)
#pragma unroll
            for (int kb = 0; kb < 2; kb++) {
                u16x8 kf = *(const u16x8*)&Ks[(l32 + 32 * kb) * 136 + 16 * c + 8 * h];
                sacc[kb] = mfma32(kf, qf[c], sacc[kb]);
            }
        unsigned int pp[16];
#pragma unroll
        for (int kb = 0; kb < 2; kb++)
#pragma unroll
            for (int r2 = 0; r2 < 8; r2++) {
                float p0 = exp2f(sacc[kb][2 * r2] * csc);
                float p1 = exp2f(sacc[kb][2 * r2 + 1] * csc);
                l_acc += p0 + p1;
                pp[kb * 8 + r2] = (unsigned int)f2bf(p0) | ((unsigned int)f2bf(p1) << 16);
            }
#pragma unroll
        for (int c = 0; c < 4; c++) {
            const int bs = (c >> 1) * 8 + (c & 1) * 4;
            unsigned int o0 = pp[bs], o1 = pp[bs + 1], o2 = pp[bs + 2], o3 = pp[bs + 3];
            unsigned int x0 = __shfl_xor(o0, 32), x1 = __shfl_xor(o1, 32);
            unsigned int x2 = __shfl_xor(o2, 32), x3 = __shfl_xor(o3, 32);
            uint4 af;
            af.x = h ? x2 : o0;
            af.y = h ? x3 : o1;
            af.z = h ? o2 : x0;
            af.w = h ? o3 : x1;
            u16x8 afr = __builtin_bit_cast(u16x8, af);
#pragma unroll
            for (int db = 0; db < 4; db++) {
                u16x8 vf = *(const u16x8*)&Vs[(32 * db + l32) * 72 + 16 * c + 8 * h];
                oacc[db] = mfma32(afr, vf, oacc[db]);
            }
        }
    }
    float l_tot = l_acc + __shfl_xor(l_acc, 32);
    if (lane < 32)
        Lw[(size_t)(b * NSPLIT + pi) * SEQ + q0 + 32 * w + l32] = l_tot;
    float rl[16];
#pragma unroll
    for (int r = 0; r < 16; r++) {
        int qr = (r & 3) + 8 * (r >> 2) + 4 * h;
        rl[r] = 1.f / __shfl(l_tot, qr);
    }
    unsigned short* ob = Opart + ((size_t)((b * NSPLIT + pi) * NQT + qt)) * 16384 + (size_t)tid * 64;
#pragma unroll
    for (int db = 0; db < 4; db++) {
        u16x8 s0, s1;
#pragma unroll
        for (int j = 0; j < 8; j++) {
            s0[j] = f2bf(oacc[db][j] * rl[j]);
            s1[j] = f2bf(oacc[db][8 + j] * rl[8 + j]);
        }
        *(u16x8*)&ob[db * 16] = s0;
        *(u16x8*)&ob[db * 16 + 8] = s1;
    }
}

// ---------------- Kernel D: combine splits (d-split, 256 blocks) -----------
__global__ __launch_bounds__(256) void attn_combine_kernel(
        const unsigned short* __restrict__ Opart, const float* __restrict__ Lw,
        float* __restrict__ out) {
    __shared__ float Ls[NSPLIT * 128];
    const int tid = threadIdx.x;
    const int w = tid >> 6, lane = tid & 63, l32 = lane & 31, h = lane >> 5;
    const int qt = blockIdx.x, b = blockIdx.y, z = blockIdx.z;
    const int q0 = qt * 128;
    for (int i = tid; i < NSPLIT * 128; i += 256) {
        int pi = i >> 7, ql = i & 127;
        Ls[i] = Lw[(size_t)(b * NSPLIT + pi) * SEQ + q0 + ql];
    }
    __syncthreads();
    int qlr[16];
    float inv[16];
#pragma unroll
    for (int r = 0; r < 16; r++) {
        qlr[r] = 32 * w + (r & 3) + 8 * (r >> 2) + 4 * h;
        float s = 0.f;
#pragma unroll
        for (int pi = 0; pi < NSPLIT; pi++) s += Ls[pi * 128 + qlr[r]];
        inv[r] = 1.f / s;
    }
    float acc[32];
#pragma unroll
    for (int i = 0; i < 32; i++) acc[i] = 0.f;
#pragma unroll
    for (int pi = 0; pi < NSPLIT; pi++) {
        float wr[16];
#pragma unroll
        for (int r = 0; r < 16; r++) wr[r] = Ls[pi * 128 + qlr[r]] * inv[r];
        const unsigned short* ob =
            Opart + ((size_t)((b * NSPLIT + pi) * NQT + qt)) * 16384 + (size_t)tid * 64;
#pragma unroll
        for (int j = 0; j < 2; j++) {
            const int db = 2 * z + j;
#pragma unroll
            for (int hf = 0; hf < 2; hf++) {
                u16x8 v8 = *(const u16x8*)&ob[db * 16 + 8 * hf];
#pragma unroll
                for (int jj = 0; jj < 8; jj++)
                    acc[j * 16 + 8 * hf + jj] += wr[8 * hf + jj] * bf2f(v8[jj]);
            }
        }
    }
#pragma unroll
    for (int j = 0; j < 2; j++) {
        const int db = 2 * z + j;
#pragma unroll
        for (int r = 0; r < 16; r++)
            out[(size_t)(b * SEQ + q0 + qlr[r]) * DK + 32 * db + l32] = acc[j * 16 + r];
    }
}

extern "C" void kernel_launch(void* const* d_in, const int* in_sizes, int n_in,
                              void* d_out, int out_size, void* d_ws, size_t ws_size,
                              hipStream_t stream) {
    const float* q  = (const float*)d_in[0];
    const float* k  = (const float*)d_in[1];
    const float* v  = (const float*)d_in[2];
    const float* wq = (const float*)d_in[3];
    const float* bq = (const float*)d_in[4];
    const float* wk = (const float*)d_in[5];
    const float* bk = (const float*)d_in[6];
    const float* wv = (const float*)d_in[7];
    const float* bv = (const float*)d_in[8];
    float* out = (float*)d_out;

    char* ws = (char*)d_ws;
    unsigned short* wT    = (unsigned short*)(ws);                    // 768 KB
    unsigned short* qp    = (unsigned short*)(ws + (1u << 20));       // 4 MB
    unsigned short* kpb   = (unsigned short*)(ws + (5u << 20));       // 4 MB
    unsigned short* vpT   = (unsigned short*)(ws + (9u << 20));       // 4 MB
    unsigned short* Opart = (unsigned short*)(ws + (13u << 20));      // 16 MB
    float* Lw             = (float*)(ws + (29u << 20));               // 256 KB

    hipLaunchKernelGGL(wt_kernel, dim3(16, 2, 3), dim3(256), 0, stream, wq, wk, wv, wT);
    hipLaunchKernelGGL(proj_kernel, dim3(512, 3), dim3(256), 0, stream,
                       q, k, v, wT, bq, bk, bv, qp, kpb, vpT);
    hipLaunchKernelGGL(attn_part_kernel, dim3(NQT, NSPLIT, NB), dim3(256), 0, stream,
                       qp, kpb, vpT, Opart, Lw);
    hipLaunchKernelGGL(attn_combine_kernel, dim3(NQT, NB, 2), dim3(256), 0, stream,
                       Opart, Lw, out);
}

// Round 9
// 271.778 us; speedup vs baseline: 1.2269x; 1.1025x over previous
//
#include <hip/hip_runtime.h>

#define DM 1024
#define DK 128
#define SEQ 4096
#define NB 4
#define NSPLIT 4
#define KSPAN (SEQ / NSPLIT)
#define NQT (SEQ / 128)

typedef float f32x4 __attribute__((ext_vector_type(4)));
typedef float f32x16 __attribute__((ext_vector_type(16)));
typedef __bf16 bf16x8 __attribute__((ext_vector_type(8)));
typedef unsigned short u16x8 __attribute__((ext_vector_type(8)));
typedef unsigned short u16x4 __attribute__((ext_vector_type(4)));

__device__ __forceinline__ unsigned short f2bf(float f) {
    unsigned int u = __builtin_bit_cast(unsigned int, f);
    u += 0x7fffu + ((u >> 16) & 1u);
    return (unsigned short)(u >> 16);
}
__device__ __forceinline__ float bf2f(unsigned short h) {
    unsigned int u = ((unsigned int)h) << 16;
    return __builtin_bit_cast(float, u);
}
__device__ __forceinline__ f32x4 mfma16(u16x8 a, u16x8 b, f32x4 c) {
    return __builtin_amdgcn_mfma_f32_16x16x32_bf16(
        __builtin_bit_cast(bf16x8, a), __builtin_bit_cast(bf16x8, b), c, 0, 0, 0);
}
__device__ __forceinline__ f32x16 mfma32(u16x8 a, u16x8 b, f32x16 c) {
    return __builtin_amdgcn_mfma_f32_32x32x16_bf16(
        __builtin_bit_cast(bf16x8, a), __builtin_bit_cast(bf16x8, b), c, 0, 0, 0);
}

// ---------------- Kernel A: wT[mat][d][k] = w[mat][k][d] (fp32 -> bf16) -----
__global__ __launch_bounds__(256) void wt_kernel(
        const float* __restrict__ wq, const float* __restrict__ wk,
        const float* __restrict__ wv, unsigned short* __restrict__ wT) {
    __shared__ unsigned short T[64 * 72];
    const int kt = blockIdx.x, dt = blockIdx.y, mat = blockIdx.z;
    const float* src = (mat == 0) ? wq : (mat == 1 ? wk : wv);
    const int tid = threadIdx.x;
    const int rb = tid >> 4, c4 = (tid & 15) * 4;
    float4 x[4];
#pragma unroll
    for (int i = 0; i < 4; i++)
        x[i] = *(const float4*)&src[(size_t)(kt * 64 + i * 16 + rb) * DK + dt * 64 + c4];
#pragma unroll
    for (int i = 0; i < 4; i++) {
        const int row = i * 16 + rb;
        T[(c4 + 0) * 72 + row] = f2bf(x[i].x);
        T[(c4 + 1) * 72 + row] = f2bf(x[i].y);
        T[(c4 + 2) * 72 + row] = f2bf(x[i].z);
        T[(c4 + 3) * 72 + row] = f2bf(x[i].w);
    }
    __syncthreads();
    const int dl = tid >> 2, ks0 = (tid & 3) * 16;
    unsigned short* dst = wT + (size_t)mat * DM * DK + (size_t)(dt * 64 + dl) * DM + kt * 64 + ks0;
#pragma unroll
    for (int j = 0; j < 2; j++)
        *(u16x8*)&dst[8 * j] = *(const u16x8*)&T[dl * 72 + ks0 + 8 * j];
}

// ---------------- Kernel B: merged projections, BK=128 (R0 baseline) -------
// R12 decision: after 8 rounds, R0's exact configuration (reg->LDS, BK=128,
// waves_per_eu(3,3), VGPR 80, 2.4M conflicts) remains the measured-best proj
// at 77us. Every variant — swizzled gll (88-92 x3), no-LDS stream (137),
// high-occupancy 32-row tiles (98, occ 46%!) — was worse: the structure is
// prefetch-liveness-limited, not occupancy- or conflict-limited. Reverted
// byte-for-byte; proj experiments closed.
__global__ __launch_bounds__(256)
__attribute__((amdgpu_waves_per_eu(3, 3)))
void proj_kernel(
        const float* __restrict__ qin, const float* __restrict__ kin,
        const float* __restrict__ vin, const unsigned short* __restrict__ wT,
        const float* __restrict__ bq, const float* __restrict__ bk,
        const float* __restrict__ bv,
        unsigned short* __restrict__ qp, unsigned short* __restrict__ kp,
        unsigned short* __restrict__ vpT) {
    __shared__ unsigned short Xs[64 * 136];
    __shared__ unsigned short Ws[128 * 136];
    const int y = blockIdx.y;
    const float* X = (y == 0) ? qin : (y == 1 ? kin : vin);
    const unsigned short* WTm = wT + (size_t)y * (DM * DK);
    const float* bias = (y == 0) ? bq : (y == 1 ? bk : bv);

    const int tid = threadIdx.x;
    const int w = tid >> 6, lane = tid & 63, l16 = lane & 15, quad = lane >> 4;
    const int t0 = blockIdx.x * 64;
    const int xr = tid >> 5, xc = (tid & 31) * 4;
    const int wr = tid >> 4, wc = (tid & 15) * 8;

    f32x4 zero = {0.f, 0.f, 0.f, 0.f};
    f32x4 acc[4][2];
#pragma unroll
    for (int mf = 0; mf < 4; mf++)
#pragma unroll
        for (int nf = 0; nf < 2; nf++) acc[mf][nf] = zero;

    float4 xv[8];
    uint4 wv[8];
#pragma unroll
    for (int i = 0; i < 8; i++) {
        xv[i] = *(const float4*)&X[(size_t)(t0 + i * 8 + xr) * DM + xc];
        wv[i] = *(const uint4*)&WTm[(size_t)(i * 16 + wr) * DM + wc];
    }

    for (int k0 = 0; k0 < DM; k0 += 128) {
        __syncthreads();
#pragma unroll
        for (int i = 0; i < 8; i++) {
            u16x4 p;
            p[0] = f2bf(xv[i].x); p[1] = f2bf(xv[i].y);
            p[2] = f2bf(xv[i].z); p[3] = f2bf(xv[i].w);
            *(u16x4*)&Xs[(i * 8 + xr) * 136 + xc] = p;
            *(u16x8*)&Ws[(i * 16 + wr) * 136 + wc] = __builtin_bit_cast(u16x8, wv[i]);
        }
        __syncthreads();
        if (k0 + 128 < DM) {
#pragma unroll
            for (int i = 0; i < 8; i++) {
                xv[i] = *(const float4*)&X[(size_t)(t0 + i * 8 + xr) * DM + (k0 + 128) + xc];
                wv[i] = *(const uint4*)&WTm[(size_t)(i * 16 + wr) * DM + (k0 + 128) + wc];
            }
        }
#pragma unroll
        for (int ks = 0; ks < 4; ks++) {
            u16x8 av[4], bvf[2];
#pragma unroll
            for (int mf = 0; mf < 4; mf++)
                av[mf] = *(const u16x8*)&Xs[(l16 + 16 * mf) * 136 + ks * 32 + quad * 8];
#pragma unroll
            for (int nf = 0; nf < 2; nf++)
                bvf[nf] = *(const u16x8*)&Ws[(l16 + 32 * w + 16 * nf) * 136 + ks * 32 + quad * 8];
#pragma unroll
            for (int mf = 0; mf < 4; mf++)
#pragma unroll
                for (int nf = 0; nf < 2; nf++)
                    acc[mf][nf] = mfma16(av[mf], bvf[nf], acc[mf][nf]);
        }
    }
    if (y < 2) {
        unsigned short* outp = y ? kp : qp;
#pragma unroll
        for (int nf = 0; nf < 2; nf++) {
            const int n = l16 + 32 * w + 16 * nf;
            const float bb = bias[n];
#pragma unroll
            for (int mf = 0; mf < 4; mf++)
#pragma unroll
                for (int r = 0; r < 4; r++)
                    outp[(size_t)(t0 + 16 * mf + quad * 4 + r) * DK + n] = f2bf(acc[mf][nf][r] + bb);
        }
    } else {
        __syncthreads();
        unsigned short* Tb = Ws;
#pragma unroll
        for (int nf = 0; nf < 2; nf++) {
            const int d = l16 + 32 * w + 16 * nf;
            const float bb = bias[d];
#pragma unroll
            for (int mf = 0; mf < 4; mf++)
#pragma unroll
                for (int r = 0; r < 4; r++)
                    Tb[d * 72 + 16 * mf + quad * 4 + r] = f2bf(acc[mf][nf][r] + bb);
        }
        __syncthreads();
        const int d2 = tid >> 1, ts = (tid & 1) * 32;
        const int b2 = t0 >> 12, tl0 = t0 & (SEQ - 1);
#pragma unroll
        for (int j = 0; j < 4; j++)
            *(u16x8*)&vpT[((size_t)(b2 * DK + d2)) * SEQ + tl0 + ts + 8 * j] =
                *(const u16x8*)&Tb[d2 * 72 + ts + 8 * j];
    }
}

// ---------------- Kernel C: flash attention partials -----------------------
// R12 change (single variable vs R0): T5 s_setprio(1) wrapped around the two
// MFMA clusters (QK^T and each PV db-burst). Blocks here are independent
// (2/CU, no cross-block sync) => waves sit at different phases => scheduler
// can favor the MFMA-issuing wave (m191: +4-7% on attn; null only on
// lockstep GEMM structures).
__global__ __launch_bounds__(256)
__attribute__((amdgpu_waves_per_eu(2, 2)))
void attn_part_kernel(
        const unsigned short* __restrict__ qp, const unsigned short* __restrict__ kp,
        const unsigned short* __restrict__ vpT,
        unsigned short* __restrict__ Opart, float* __restrict__ Lw) {
    __shared__ unsigned short Ks[64 * 136];  // [key][d]
    __shared__ unsigned short Vs[128 * 72];  // [d][key]

    const int tid = threadIdx.x;
    const int w = tid >> 6, lane = tid & 63, l32 = lane & 31, h = lane >> 5;
    const int qt = blockIdx.x, pi = blockIdx.y, b = blockIdx.z;
    const int q0 = qt * 128;
    const int kbase = pi * KSPAN;
    const float csc = 0.08838834764831845f * 1.4426950408889634f;  // scale*log2(e)

    u16x8 qf[8];
    {
        const unsigned short* qrow = qp + (size_t)(b * SEQ + q0 + 32 * w + l32) * DK + 8 * h;
#pragma unroll
        for (int c = 0; c < 8; c++) qf[c] = *(const u16x8*)&qrow[16 * c];
    }

    f32x16 oacc[4];
#pragma unroll
    for (int i = 0; i < 4; i++)
#pragma unroll
        for (int j = 0; j < 16; j++) oacc[i][j] = 0.f;
    float l_acc = 0.f;

    const int krow = tid >> 2, kch = (tid & 3) * 8;
    const int vrow = tid >> 1, voff = (tid & 1) * 8;
    uint4 kbuf[4], vbuf[4];
    {
        const unsigned short* kg = kp + (size_t)(b * SEQ + kbase + krow) * DK + kch;
        const unsigned short* vg = vpT + (size_t)(b * DK + vrow) * SEQ + kbase + voff;
#pragma unroll
        for (int i = 0; i < 4; i++) {
            kbuf[i] = *(const uint4*)&kg[32 * i];
            vbuf[i] = *(const uint4*)&vg[16 * i];
        }
    }

    for (int it = 0; it < KSPAN / 64; it++) {
        __syncthreads();
#pragma unroll
        for (int i = 0; i < 4; i++) {
            *(u16x8*)&Ks[krow * 136 + kch + 32 * i] = __builtin_bit_cast(u16x8, kbuf[i]);
            *(u16x8*)&Vs[vrow * 72 + voff + 16 * i] = __builtin_bit_cast(u16x8, vbuf[i]);
        }
        __syncthreads();
        if (it + 1 < KSPAN / 64) {
            const int kn = kbase + (it + 1) * 64;
            const unsigned short* kg = kp + (size_t)(b * SEQ + kn + krow) * DK + kch;
            const unsigned short* vg = vpT + (size_t)(b * DK + vrow) * SEQ + kn + voff;
#pragma unroll
            for (int i = 0; i < 4; i++) {
                kbuf[i] = *(const uint4*)&kg[32 * i];
                vbuf[i] = *(const uint4*)&vg[16 * i];
            }
        }
        f32x16 sacc[2];
#pragma unroll
        for (int kb = 0; kb < 2; kb++)
#pragma unroll
            for (int j = 0; j < 16; j++) sacc[kb][j] = 0.f;
        __builtin_amdgcn_s_setprio(1);
#pragma unroll
        for (int c = 0; c < 8; c++)
#pragma unroll
            for (int kb = 0; kb < 2; kb++) {
                u16x8 kf = *(const u16x8*)&Ks[(l32 + 32 * kb) * 136 + 16 * c + 8 * h];
                sacc[kb] = mfma32(kf, qf[c], sacc[kb]);
            }
        __builtin_amdgcn_s_setprio(0);
        unsigned int pp[16];
#pragma unroll
        for (int kb = 0; kb < 2; kb++)
#pragma unroll
            for (int r2 = 0; r2 < 8; r2++) {
                float p0 = exp2f(sacc[kb][2 * r2] * csc);
                float p1 = exp2f(sacc[kb][2 * r2 + 1] * csc);
                l_acc += p0 + p1;
                pp[kb * 8 + r2] = (unsigned int)f2bf(p0) | ((unsigned int)f2bf(p1) << 16);
            }
#pragma unroll
        for (int c = 0; c < 4; c++) {
            const int bs = (c >> 1) * 8 + (c & 1) * 4;
            unsigned int o0 = pp[bs], o1 = pp[bs + 1], o2 = pp[bs + 2], o3 = pp[bs + 3];
            unsigned int x0 = __shfl_xor(o0, 32), x1 = __shfl_xor(o1, 32);
            unsigned int x2 = __shfl_xor(o2, 32), x3 = __shfl_xor(o3, 32);
            uint4 af;
            af.x = h ? x2 : o0;
            af.y = h ? x3 : o1;
            af.z = h ? o2 : x0;
            af.w = h ? o3 : x1;
            u16x8 afr = __builtin_bit_cast(u16x8, af);
            __builtin_amdgcn_s_setprio(1);
#pragma unroll
            for (int db = 0; db < 4; db++) {
                u16x8 vf = *(const u16x8*)&Vs[(32 * db + l32) * 72 + 16 * c + 8 * h];
                oacc[db] = mfma32(afr, vf, oacc[db]);
            }
            __builtin_amdgcn_s_setprio(0);
        }
    }
    float l_tot = l_acc + __shfl_xor(l_acc, 32);
    if (lane < 32)
        Lw[(size_t)(b * NSPLIT + pi) * SEQ + q0 + 32 * w + l32] = l_tot;
    float rl[16];
#pragma unroll
    for (int r = 0; r < 16; r++) {
        int qr = (r & 3) + 8 * (r >> 2) + 4 * h;
        rl[r] = 1.f / __shfl(l_tot, qr);
    }
    unsigned short* ob = Opart + ((size_t)((b * NSPLIT + pi) * NQT + qt)) * 16384 + (size_t)tid * 64;
#pragma unroll
    for (int db = 0; db < 4; db++) {
        u16x8 s0, s1;
#pragma unroll
        for (int j = 0; j < 8; j++) {
            s0[j] = f2bf(oacc[db][j] * rl[j]);
            s1[j] = f2bf(oacc[db][8 + j] * rl[8 + j]);
        }
        *(u16x8*)&ob[db * 16] = s0;
        *(u16x8*)&ob[db * 16 + 8] = s1;
    }
}

// ---------------- Kernel D: combine splits (d-split, 256 blocks) -----------
__global__ __launch_bounds__(256) void attn_combine_kernel(
        const unsigned short* __restrict__ Opart, const float* __restrict__ Lw,
        float* __restrict__ out) {
    __shared__ float Ls[NSPLIT * 128];
    const int tid = threadIdx.x;
    const int w = tid >> 6, lane = tid & 63, l32 = lane & 31, h = lane >> 5;
    const int qt = blockIdx.x, b = blockIdx.y, z = blockIdx.z;
    const int q0 = qt * 128;
    for (int i = tid; i < NSPLIT * 128; i += 256) {
        int pi = i >> 7, ql = i & 127;
        Ls[i] = Lw[(size_t)(b * NSPLIT + pi) * SEQ + q0 + ql];
    }
    __syncthreads();
    int qlr[16];
    float inv[16];
#pragma unroll
    for (int r = 0; r < 16; r++) {
        qlr[r] = 32 * w + (r & 3) + 8 * (r >> 2) + 4 * h;
        float s = 0.f;
#pragma unroll
        for (int pi = 0; pi < NSPLIT; pi++) s += Ls[pi * 128 + qlr[r]];
        inv[r] = 1.f / s;
    }
    float acc[32];
#pragma unroll
    for (int i = 0; i < 32; i++) acc[i] = 0.f;
#pragma unroll
    for (int pi = 0; pi < NSPLIT; pi++) {
        float wr[16];
#pragma unroll
        for (int r = 0; r < 16; r++) wr[r] = Ls[pi * 128 + qlr[r]] * inv[r];
        const unsigned short* ob =
            Opart + ((size_t)((b * NSPLIT + pi) * NQT + qt)) * 16384 + (size_t)tid * 64;
#pragma unroll
        for (int j = 0; j < 2; j++) {
            const int db = 2 * z + j;
#pragma unroll
            for (int hf = 0; hf < 2; hf++) {
                u16x8 v8 = *(const u16x8*)&ob[db * 16 + 8 * hf];
#pragma unroll
                for (int jj = 0; jj < 8; jj++)
                    acc[j * 16 + 8 * hf + jj] += wr[8 * hf + jj] * bf2f(v8[jj]);
            }
        }
    }
#pragma unroll
    for (int j = 0; j < 2; j++) {
        const int db = 2 * z + j;
#pragma unroll
        for (int r = 0; r < 16; r++)
            out[(size_t)(b * SEQ + q0 + qlr[r]) * DK + 32 * db + l32] = acc[j * 16 + r];
    }
}

extern "C" void kernel_launch(void* const* d_in, const int* in_sizes, int n_in,
                              void* d_out, int out_size, void* d_ws, size_t ws_size,
                              hipStream_t stream) {
    const float* q  = (const float*)d_in[0];
    const float* k  = (const float*)d_in[1];
    const float* v  = (const float*)d_in[2];
    const float* wq = (const float*)d_in[3];
    const float* bq = (const float*)d_in[4];
    const float* wk = (const float*)d_in[5];
    const float* bk = (const float*)d_in[6];
    const float* wv = (const float*)d_in[7];
    const float* bv = (const float*)d_in[8];
    float* out = (float*)d_out;

    char* ws = (char*)d_ws;
    unsigned short* wT    = (unsigned short*)(ws);                    // 768 KB
    unsigned short* qp    = (unsigned short*)(ws + (1u << 20));       // 4 MB
    unsigned short* kpb   = (unsigned short*)(ws + (5u << 20));       // 4 MB
    unsigned short* vpT   = (unsigned short*)(ws + (9u << 20));       // 4 MB
    unsigned short* Opart = (unsigned short*)(ws + (13u << 20));      // 16 MB
    float* Lw             = (float*)(ws + (29u << 20));               // 256 KB

    hipLaunchKernelGGL(wt_kernel, dim3(16, 2, 3), dim3(256), 0, stream, wq, wk, wv, wT);
    hipLaunchKernelGGL(proj_kernel, dim3(256, 3), dim3(256), 0, stream,
                       q, k, v, wT, bq, bk, bv, qp, kpb, vpT);
    hipLaunchKernelGGL(attn_part_kernel, dim3(NQT, NSPLIT, NB), dim3(256), 0, stream,
                       qp, kpb, vpT, Opart, Lw);
    hipLaunchKernelGGL(attn_combine_kernel, dim3(NQT, NB, 2), dim3(256), 0, stream,
                       Opart, Lw, out);
}